// Round 1
// baseline (2731.609 us; speedup 1.0000x reference)
//
#include <hip/hip_runtime.h>
#include <hip/hip_bf16.h>
#include <math.h>

#define B_  2
#define S_  2048
#define D_  1024
#define H_  16
#define HD_ 64
#define M_  (B_*S_)      // 4096 rows (b,s)
#define BH_ (B_*H_)      // 32

// scratch in device globals (ws_size unknown); ~80MB total
__device__ float g_kp[(size_t)M_ * D_];   // roped key projection
__device__ float g_vp[(size_t)M_ * D_];   // roped value projection
__device__ float g_qr[(size_t)M_ * D_];   // roped query
__device__ float g_oh[(size_t)M_ * D_];   // attention out, (B,H,S,hd) flat
__device__ float g_m [BH_ * S_];          // per-(b,h,k) column max
__device__ float g_z [BH_ * S_];          // per-(b,h,k) column denom
__device__ float g_tab[S_ * 64];          // cos/sin interleaved per (s, f<32)

// ------------------------------------------------ cos/sin table
__global__ void k_table(const int* __restrict__ pos){
  int i = blockIdx.x * 256 + threadIdx.x;
  if (i >= S_ * 32) return;
  int s = i >> 5, f = i & 31;
  float ang = (float)pos[s] * powf(10000.0f, -(float)f * (1.0f/32.0f));
  g_tab[2*i]   = cosf(ang);
  g_tab[2*i+1] = sinf(ang);
}

// ------------------------------------------------ RoPE elementwise
// flat (B,S,D) buffer == (B,H,S,hd) reshape: s=(idx/64)%2048, d=idx%64
// MODE 0: in_ -> g_qr ; 1: g_kp in place ; 2: g_vp in place
template<int MODE>
__global__ void k_rope(const float* __restrict__ in_){
  int i = blockIdx.x * 256 + threadIdx.x;
  if (i >= (M_ * D_) / 2) return;
  const float* in  = (MODE==0) ? in_  : (MODE==1) ? g_kp : g_vp;
  float*       out = (MODE==0) ? g_qr : (MODE==1) ? g_kp : g_vp;
  int grp = i >> 5;           // 64-element group
  int d   = i & 31;           // pair (d, d+32)
  int s   = grp & (S_ - 1);
  size_t base = (size_t)grp * 64;
  float x1 = in[base + d];
  float x2 = in[base + d + 32];
  float c  = g_tab[(s*32 + d)*2];
  float sn = g_tab[(s*32 + d)*2 + 1];
  out[base + d]      = x1 * c - x2 * sn;
  out[base + d + 32] = x2 * c + x1 * sn;
}

// ------------------------------------------------ C = A * W^T + bias  (M_ x D_)
// MODE 0: C=g_kp, A=param ; 1: C=g_vp, A=param ;
// MODE 2: C=Cout param, A = g_oh with merge-heads gather x[b,s,h*64+d]=oh[b,h,s,d]
template<int MODE>
__global__ __launch_bounds__(256) void k_gemm(const float* __restrict__ A,
                                              const float* __restrict__ W,
                                              const float* __restrict__ bias,
                                              float* __restrict__ Cout){
  __shared__ float As[16][64];   // [k][m] transposed
  __shared__ float Bs[16][64];   // [k][n] transposed
  float* C = (MODE==0) ? g_kp : (MODE==1) ? g_vp : Cout;
  const int t  = threadIdx.x;
  const int tx = t & 15, ty = t >> 4;
  const int rowBase = blockIdx.y * 64;
  const int colBase = blockIdx.x * 64;
  const int lr = t >> 2;          // 0..63
  const int lc = (t & 3) * 4;     // 0,4,8,12
  float acc[4][4] = {};
  for (int k0 = 0; k0 < D_; k0 += 16){
    const int r = rowBase + lr;
    const int c = k0 + lc;
    float4 av;
    if (MODE == 2){
      int b = r >> 11, s = r & (S_ - 1);
      av = *(const float4*)(g_oh + ((size_t)(b*H_ + (c >> 6)) * S_ + s) * HD_ + (c & 63));
    } else {
      av = *(const float4*)(A + (size_t)r * D_ + c);
    }
    float4 wv = *(const float4*)(W + (size_t)(colBase + lr) * D_ + c);
    __syncthreads();
    As[lc+0][lr]=av.x; As[lc+1][lr]=av.y; As[lc+2][lr]=av.z; As[lc+3][lr]=av.w;
    Bs[lc+0][lr]=wv.x; Bs[lc+1][lr]=wv.y; Bs[lc+2][lr]=wv.z; Bs[lc+3][lr]=wv.w;
    __syncthreads();
    #pragma unroll
    for (int kk = 0; kk < 16; ++kk){
      float4 a4 = *(const float4*)&As[kk][ty*4];
      float4 b4 = *(const float4*)&Bs[kk][tx*4];
      float a[4] = {a4.x, a4.y, a4.z, a4.w};
      float b[4] = {b4.x, b4.y, b4.z, b4.w};
      #pragma unroll
      for (int i=0;i<4;++i)
        #pragma unroll
        for (int j=0;j<4;++j)
          acc[i][j] += a[i] * b[j];
    }
  }
  #pragma unroll
  for (int i=0;i<4;++i){
    const int rr = rowBase + ty*4 + i;
    float4 o;
    o.x = acc[i][0] + bias[colBase + tx*4 + 0];
    o.y = acc[i][1] + bias[colBase + tx*4 + 1];
    o.z = acc[i][2] + bias[colBase + tx*4 + 2];
    o.w = acc[i][3] + bias[colBase + tx*4 + 3];
    *(float4*)(C + (size_t)rr * D_ + colBase + tx*4) = o;
  }
}

// ------------------------------------------------ pass 1: column max / denom
// softmax over the QUERY axis per key-column k: m_k = max_q s_qk, Z_k = sum_q exp(s_qk-m_k)
// diagonal score forced to 0 (reference multiplies scores by (1-eye) BEFORE softmax)
__global__ __launch_bounds__(256) void k_pass1(){
  __shared__ float Qs[64][64];
  __shared__ float sm[4][64];
  __shared__ float sz[4][64];
  const int bh = blockIdx.y;
  const int k0 = blockIdx.x * 64;
  const float* Qb = g_qr + (size_t)bh * S_ * HD_;
  const float* Kb = g_kp + (size_t)bh * S_ * HD_;
  const int t  = threadIdx.x;
  const int ky = t & 63, qg = t >> 6;
  float kr[64];
  #pragma unroll
  for (int d4 = 0; d4 < 16; ++d4){
    float4 v = *(const float4*)(Kb + (size_t)(k0 + ky) * HD_ + d4*4);
    kr[d4*4+0]=v.x; kr[d4*4+1]=v.y; kr[d4*4+2]=v.z; kr[d4*4+3]=v.w;
  }
  float m = -INFINITY, z = 0.f;
  const int kg = k0 + ky;
  for (int q0 = 0; q0 < S_; q0 += 64){
    __syncthreads();
    for (int i = t; i < 64*16; i += 256){
      int r = i >> 4, c = (i & 15) * 4;
      *(float4*)&Qs[r][c] = *(const float4*)(Qb + (size_t)(q0 + r) * HD_ + c);
    }
    __syncthreads();
    for (int qi = 0; qi < 16; ++qi){
      int ql = qg*16 + qi;
      float s = 0.f;
      #pragma unroll
      for (int d4 = 0; d4 < 16; ++d4){
        float4 qv = *(const float4*)&Qs[ql][d4*4];
        s += qv.x*kr[d4*4+0] + qv.y*kr[d4*4+1] + qv.z*kr[d4*4+2] + qv.w*kr[d4*4+3];
      }
      s *= 0.125f;                 // 1/sqrt(64)
      if (q0 + ql == kg) s = 0.f;  // zeroed diagonal still participates
      if (s > m){ z = z * __expf(m - s) + 1.f; m = s; }
      else      { z += __expf(s - m); }
    }
  }
  sm[qg][ky] = m; sz[qg][ky] = z;
  __syncthreads();
  if (t < 64){
    float M = sm[0][t];
    #pragma unroll
    for (int g = 1; g < 4; ++g) M = fmaxf(M, sm[g][t]);
    float Z = 0.f;
    #pragma unroll
    for (int g = 0; g < 4; ++g) Z += sz[g][t] * __expf(sm[g][t] - M);
    g_m[bh*S_ + k0 + t] = M;
    g_z[bh*S_ + k0 + t] = Z;
  }
}

// ------------------------------------------------ pass 2: out[q,d] = sum_k exp(s_qk-m_k)/Z_k * v[k,d]
__global__ __launch_bounds__(256) void k_pass2(){
  __shared__ float Qt[64][64];   // [d][q]
  __shared__ float KV[64][64];   // K^T [d][k], then V [k][d]
  __shared__ float Es[64][68];   // [k][q], padded for bank spread
  const int bh = blockIdx.y;
  const int q0 = blockIdx.x * 64;
  const float* Qb = g_qr + (size_t)bh * S_ * HD_;
  const float* Kb = g_kp + (size_t)bh * S_ * HD_;
  const float* Vb = g_vp + (size_t)bh * S_ * HD_;
  const int t  = threadIdx.x;
  const int tx = t & 15, ty = t >> 4;
  // Q tile, transposed (persistent)
  #pragma unroll
  for (int u = 0; u < 4; ++u){
    int i = t + u*256, r = i >> 4, c = (i & 15) * 4;
    float4 v = *(const float4*)(Qb + (size_t)(q0 + r) * HD_ + c);
    Qt[c+0][r]=v.x; Qt[c+1][r]=v.y; Qt[c+2][r]=v.z; Qt[c+3][r]=v.w;
  }
  float acc[4][4] = {};
  for (int k0 = 0; k0 < S_; k0 += 64){
    float4 kk4[4];
    #pragma unroll
    for (int u = 0; u < 4; ++u){
      int i = t + u*256, r = i >> 4, c = (i & 15) * 4;
      kk4[u] = *(const float4*)(Kb + (size_t)(k0 + r) * HD_ + c);
    }
    __syncthreads();   // prev iter done reading KV(=V) and Es; Qt stores covered on iter 0
    #pragma unroll
    for (int u = 0; u < 4; ++u){
      int i = t + u*256, r = i >> 4, c = (i & 15) * 4;
      KV[c+0][r]=kk4[u].x; KV[c+1][r]=kk4[u].y; KV[c+2][r]=kk4[u].z; KV[c+3][r]=kk4[u].w;
    }
    __syncthreads();
    // stage A: scores for q = q0+tx*4+i, k = k0+ty*4+j   (sc[j][i])
    float sc[4][4] = {};
    #pragma unroll
    for (int d = 0; d < 64; ++d){
      float4 a4 = *(const float4*)&Qt[d][tx*4];
      float4 b4 = *(const float4*)&KV[d][ty*4];
      float a[4] = {a4.x, a4.y, a4.z, a4.w};
      float b[4] = {b4.x, b4.y, b4.z, b4.w};
      #pragma unroll
      for (int j=0;j<4;++j)
        #pragma unroll
        for (int i=0;i<4;++i)
          sc[j][i] += a[i] * b[j];
    }
    // prefetch V tile + column stats
    float4 vv[4];
    #pragma unroll
    for (int u = 0; u < 4; ++u){
      int i = t + u*256, r = i >> 4, c = (i & 15) * 4;
      vv[u] = *(const float4*)(Vb + (size_t)(k0 + r) * HD_ + c);
    }
    float mr[4], rz[4];
    #pragma unroll
    for (int j=0;j<4;++j){
      int kg = k0 + ty*4 + j;
      mr[j] = g_m[bh*S_ + kg];
      rz[j] = 1.0f / g_z[bh*S_ + kg];
    }
    __syncthreads();   // done reading K^T from KV
    #pragma unroll
    for (int u = 0; u < 4; ++u){
      int i = t + u*256, r = i >> 4, c = (i & 15) * 4;
      *(float4*)&KV[r][c] = vv[u];   // V row-major
    }
    #pragma unroll
    for (int j=0;j<4;++j){
      int kg = k0 + ty*4 + j;
      float mm = mr[j], rr = rz[j];
      float4 e;
      e.x = ((q0+tx*4+0)==kg ? __expf(-mm) : __expf(sc[j][0]*0.125f - mm)) * rr;
      e.y = ((q0+tx*4+1)==kg ? __expf(-mm) : __expf(sc[j][1]*0.125f - mm)) * rr;
      e.z = ((q0+tx*4+2)==kg ? __expf(-mm) : __expf(sc[j][2]*0.125f - mm)) * rr;
      e.w = ((q0+tx*4+3)==kg ? __expf(-mm) : __expf(sc[j][3]*0.125f - mm)) * rr;
      *(float4*)&Es[ty*4+j][tx*4] = e;
    }
    __syncthreads();
    // stage B: out[q=ty*4+i][d=tx*4+j] += E[q][k] * V[k][d]
    #pragma unroll
    for (int k = 0; k < 64; ++k){
      float4 a4 = *(const float4*)&Es[k][ty*4];
      float4 b4 = *(const float4*)&KV[k][tx*4];
      float a[4] = {a4.x, a4.y, a4.z, a4.w};
      float b[4] = {b4.x, b4.y, b4.z, b4.w};
      #pragma unroll
      for (int i=0;i<4;++i)
        #pragma unroll
        for (int j=0;j<4;++j)
          acc[i][j] += a[i] * b[j];
    }
  }
  float* Ob = g_oh + (size_t)bh * S_ * HD_;
  #pragma unroll
  for (int i=0;i<4;++i){
    float4 o = {acc[i][0], acc[i][1], acc[i][2], acc[i][3]};
    *(float4*)(Ob + (size_t)(q0 + ty*4 + i) * HD_ + tx*4) = o;
  }
}

extern "C" void kernel_launch(void* const* d_in, const int* in_sizes, int n_in,
                              void* d_out, int out_size, void* d_ws, size_t ws_size,
                              hipStream_t stream) {
  const float* query = (const float*)d_in[0];
  const float* key   = (const float*)d_in[1];
  const float* value = (const float*)d_in[2];
  const int*   pos   = (const int*)  d_in[3];
  const float* Wk    = (const float*)d_in[4];
  const float* bk    = (const float*)d_in[5];
  const float* Wv    = (const float*)d_in[6];
  const float* bv    = (const float*)d_in[7];
  const float* Wo    = (const float*)d_in[8];
  const float* bo    = (const float*)d_in[9];
  float* out = (float*)d_out;

  k_table<<<(S_*32 + 255)/256, 256, 0, stream>>>(pos);

  dim3 gGemm(D_/64, M_/64);
  k_gemm<0><<<gGemm, 256, 0, stream>>>(key,   Wk, bk, nullptr);  // -> g_kp
  k_gemm<1><<<gGemm, 256, 0, stream>>>(value, Wv, bv, nullptr);  // -> g_vp

  int nPairs = (M_ * D_) / 2;
  k_rope<0><<<(nPairs + 255)/256, 256, 0, stream>>>(query);      // query -> g_qr
  k_rope<1><<<(nPairs + 255)/256, 256, 0, stream>>>(nullptr);    // g_kp in place
  k_rope<2><<<(nPairs + 255)/256, 256, 0, stream>>>(nullptr);    // g_vp in place

  dim3 gAtt(S_/64, BH_);
  k_pass1<<<gAtt, 256, 0, stream>>>();
  k_pass2<<<gAtt, 256, 0, stream>>>();

  k_gemm<2><<<gGemm, 256, 0, stream>>>(nullptr, Wo, bo, out);    // g_oh -> out
}

// Round 3
// 417.881 us; speedup vs baseline: 6.5368x; 6.5368x over previous
//
#include <hip/hip_runtime.h>
#include <hip/hip_bf16.h>
#include <math.h>

#define B_  2
#define S_  2048
#define D_  1024
#define H_  16
#define HD_ 64
#define M_  (B_*S_)      // 4096 (b,s) rows
#define BH_ (B_*H_)      // 32
#define QKSCALE 0.18033688011112042f   // 0.125 * log2(e), folded into Q

typedef __attribute__((ext_vector_type(8)))  short  bf16x8;
typedef __attribute__((ext_vector_type(4)))  float  f32x4;

#define MFMA16(a,b,c) __builtin_amdgcn_mfma_f32_16x16x32_bf16(a,b,c,0,0,0)

// ---- device scratch (~88 MB) ----
__device__ float          g_kp[(size_t)M_ * D_];     // K projection fp32
__device__ float          g_vp[(size_t)M_ * D_];     // V projection fp32
__device__ unsigned short g_key16[(size_t)M_ * D_];
__device__ unsigned short g_val16[(size_t)M_ * D_];
__device__ unsigned short g_wk16[(size_t)D_ * D_];
__device__ unsigned short g_wv16[(size_t)D_ * D_];
__device__ unsigned short g_wo16[(size_t)D_ * D_];
__device__ unsigned short g_q16[(size_t)M_ * D_];    // roped+scaled Q  [bh][s][64]
__device__ unsigned short g_k16[(size_t)M_ * D_];    // roped K        [bh][s][64]
__device__ unsigned short g_v16t[(size_t)M_ * D_];   // roped,*1/Z, V^T [bh][64 d][2048 s]
__device__ unsigned short g_x16[(size_t)M_ * D_];    // attn out, (b,s,D) layout
__device__ float          g_rz[BH_ * S_];            // 1/Z per (bh, key s)
__device__ float          g_tab[S_ * 64];            // cos/sin interleaved

static __device__ __forceinline__ unsigned short f2b(float x){
  union { float f; unsigned u; } v; v.f = x;
  unsigned r = v.u + 0x7FFFu + ((v.u >> 16) & 1u);   // RNE
  return (unsigned short)(r >> 16);
}
static __device__ __forceinline__ unsigned pk2(float a, float b){
  return (unsigned)f2b(a) | ((unsigned)f2b(b) << 16);
}

// ------------------------------------------------ cos/sin table
__global__ void k_table(const int* __restrict__ pos){
  int i = blockIdx.x * 256 + threadIdx.x;
  if (i >= S_ * 32) return;
  int s = i >> 5, f = i & 31;
  float ang = (float)pos[s] * powf(10000.0f, -(float)f * (1.0f/32.0f));
  g_tab[2*i]   = cosf(ang);
  g_tab[2*i+1] = sinf(ang);
}

// ------------------------------------------------ fp32 -> bf16 bulk convert
__global__ void k_cvt(const float* __restrict__ in, unsigned short* __restrict__ out, int n8){
  int i = blockIdx.x * 256 + threadIdx.x;
  if (i >= n8) return;
  float4 a = *(const float4*)(in + (size_t)i*8);
  float4 b = *(const float4*)(in + (size_t)i*8 + 4);
  union { unsigned short s[8]; float4 v; } w;
  w.s[0]=f2b(a.x); w.s[1]=f2b(a.y); w.s[2]=f2b(a.z); w.s[3]=f2b(a.w);
  w.s[4]=f2b(b.x); w.s[5]=f2b(b.y); w.s[6]=f2b(b.z); w.s[7]=f2b(b.w);
  *(float4*)(out + (size_t)i*8) = w.v;
}

// ------------------------------------------------ RoPE -> bf16 (flat groups are (b,h,s))
// MODE 0: query -> g_q16 (scaled by QKSCALE);  MODE 1: g_kp -> g_k16
template<int MODE>
__global__ void k_rope16(const float* __restrict__ in){
  const int i = blockIdx.x * 256 + threadIdx.x;   // pair index
  const float* src = (MODE == 0) ? in : g_kp;
  unsigned short* dst = (MODE == 0) ? g_q16 : g_k16;
  const int grp = i >> 5, d = i & 31;
  const int s = grp & (S_ - 1);
  const size_t base = (size_t)grp * 64;
  const float x1 = src[base + d];
  const float x2 = src[base + d + 32];
  const float c  = g_tab[(s*32 + d)*2];
  const float sn = g_tab[(s*32 + d)*2 + 1];
  float o1 = x1*c - x2*sn;
  float o2 = x2*c + x1*sn;
  if (MODE == 0){ o1 *= QKSCALE; o2 *= QKSCALE; }
  dst[base + d]      = f2b(o1);
  dst[base + d + 32] = f2b(o2);
}

// ------------------------------------------------ bf16 MFMA GEMM: C = A * W^T + bias (fp32 out)
// A [4096][1024] bf16, W [1024][1024] bf16 row-major, tile 128x128, BK=64
__global__ __launch_bounds__(256) void k_gemm(const unsigned short* __restrict__ A,
                                              const unsigned short* __restrict__ W,
                                              const float* __restrict__ bias,
                                              float* __restrict__ C){
  __shared__ __align__(16) unsigned short As[128*64];
  __shared__ __align__(16) unsigned short Bs[128*64];
  const int t = threadIdx.x, l = t & 63, wid = t >> 6;
  const int wm = wid >> 1, wn = wid & 1;
  const int rowB = blockIdx.y * 128, colB = blockIdx.x * 128;
  f32x4 acc[4][4];
  #pragma unroll
  for (int i = 0; i < 4; ++i)
    #pragma unroll
    for (int j = 0; j < 4; ++j)
      #pragma unroll
      for (int r = 0; r < 4; ++r) acc[i][j][r] = 0.f;

  const int srow = t >> 3, scb = (t & 7) * 16;
  float4 ar[4], br[4];
#define GLOADG(K0) \
  for (int u = 0; u < 4; ++u){ \
    const int row = srow + u*32; \
    ar[u] = *(const float4*)((const char*)(A + (size_t)(rowB+row)*D_ + (K0)) + scb); \
    br[u] = *(const float4*)((const char*)(W + (size_t)(colB+row)*D_ + (K0)) + scb); \
  }
  GLOADG(0);
  for (int k0 = 0; k0 < D_; k0 += 64){
    __syncthreads();
    #pragma unroll
    for (int u = 0; u < 4; ++u){
      const int row = srow + u*32;
      const int off = row*128 + (scb ^ ((row & 7) << 4));
      *(float4*)((char*)As + off) = ar[u];
      *(float4*)((char*)Bs + off) = br[u];
    }
    __syncthreads();
    if (k0 + 64 < D_){ GLOADG(k0 + 64); }
    #pragma unroll
    for (int kk = 0; kk < 2; ++kk){
      const int cb = kk*64 + (l >> 4) * 16;
      bf16x8 af[4], bfr[4];
      #pragma unroll
      for (int mi = 0; mi < 4; ++mi){
        const int row = wm*64 + mi*16 + (l & 15);
        af[mi] = *(const bf16x8*)((const char*)As + row*128 + (cb ^ ((row & 7) << 4)));
      }
      #pragma unroll
      for (int ni = 0; ni < 4; ++ni){
        const int row = wn*64 + ni*16 + (l & 15);
        bfr[ni] = *(const bf16x8*)((const char*)Bs + row*128 + (cb ^ ((row & 7) << 4)));
      }
      #pragma unroll
      for (int mi = 0; mi < 4; ++mi)
        #pragma unroll
        for (int ni = 0; ni < 4; ++ni)
          acc[mi][ni] = MFMA16(af[mi], bfr[ni], acc[mi][ni]);
    }
  }
#undef GLOADG
  #pragma unroll
  for (int mi = 0; mi < 4; ++mi){
    #pragma unroll
    for (int ni = 0; ni < 4; ++ni){
      const int col = colB + wn*64 + ni*16 + (l & 15);
      const float bb = bias[col];
      #pragma unroll
      for (int r = 0; r < 4; ++r){
        const int row = rowB + wm*64 + mi*16 + (l >> 4)*4 + r;
        C[(size_t)row * D_ + col] = acc[mi][ni][r] + bb;
      }
    }
  }
}

// ------------------------------------------------ pass 1: Z_k = sum_q exp(s_qk), diag s=0
__global__ __launch_bounds__(256) void k_pass1(){
  const int t = threadIdx.x, l = t & 63, wid = t >> 6;
  const int bh = blockIdx.y;
  const int k0 = blockIdx.x * 128 + wid * 32;
  const unsigned short* Qp = g_q16 + (size_t)bh * S_ * HD_;
  const unsigned short* Kp = g_k16 + (size_t)bh * S_ * HD_;
  bf16x8 bk[2][2];
  #pragma unroll
  for (int kb = 0; kb < 2; ++kb){
    const unsigned short* kr = Kp + (size_t)(k0 + kb*16 + (l & 15)) * HD_ + (l >> 4) * 8;
    bk[kb][0] = *(const bf16x8*)(kr);
    bk[kb][1] = *(const bf16x8*)(kr + 32);
  }
  float z0 = 0.f, z1 = 0.f;
  for (int q0 = 0; q0 < S_; q0 += 16){
    const unsigned short* qr = Qp + (size_t)(q0 + (l & 15)) * HD_ + (l >> 4) * 8;
    bf16x8 a0 = *(const bf16x8*)(qr);
    bf16x8 a1 = *(const bf16x8*)(qr + 32);
    #pragma unroll
    for (int kb = 0; kb < 2; ++kb){
      f32x4 c = {0.f, 0.f, 0.f, 0.f};
      c = MFMA16(a0, bk[kb][0], c);
      c = MFMA16(a1, bk[kb][1], c);
      const int kg = k0 + kb*16 + (l & 15);
      float zz = 0.f;
      #pragma unroll
      for (int r = 0; r < 4; ++r){
        const float e = exp2f(c[r]);
        zz += (q0 + (l >> 4)*4 + r == kg) ? 1.0f : e;
      }
      if (kb == 0) z0 += zz; else z1 += zz;
    }
  }
  z0 += __shfl_xor(z0, 16); z0 += __shfl_xor(z0, 32);
  z1 += __shfl_xor(z1, 16); z1 += __shfl_xor(z1, 32);
  if (l < 16){
    g_rz[bh*S_ + k0 + l]      = 1.0f / z0;
    g_rz[bh*S_ + k0 + 16 + l] = 1.0f / z1;
  }
}

// ------------------------------------------------ V fixup: rope + *1/Z + transpose -> bf16 [bh][d][s]
__global__ __launch_bounds__(256) void k_vfix(){
  __shared__ __align__(16) float tile[64][68];
  const int t = threadIdx.x;
  const int bh = blockIdx.y;
  const int s0 = blockIdx.x * 64;
  #pragma unroll
  for (int u = 0; u < 4; ++u){
    const int i = t + u*256;
    const int row = i >> 4, c4 = (i & 15) * 4;
    *(float4*)&tile[row][c4] = *(const float4*)(g_vp + (size_t)(bh*S_ + s0 + row) * HD_ + c4);
  }
  __syncthreads();
  const int d = t >> 2;
  const int sc = (t & 3) * 16;
  const int f = d & 31;
  const float rs = (d < 32) ? -1.f : 1.f;
  unsigned short* dst = g_v16t + (size_t)(bh*HD_ + d) * S_ + s0 + sc;
  #pragma unroll
  for (int j = 0; j < 16; ++j){
    const int s = sc + j;
    const int sa = s0 + s;
    const float c  = g_tab[(sa*32 + f)*2];
    const float sn = g_tab[(sa*32 + f)*2 + 1];
    const float x1 = tile[s][d];
    const float x2 = tile[s][d ^ 32];
    float o = x1 * c + rs * x2 * sn;
    o *= g_rz[bh*S_ + sa];
    dst[j] = f2b(o);
  }
}

// ------------------------------------------------ pass 2: out[q,:] = sum_k exp(s_qk) * V'[k,:]
// 4 waves x 16 q-rows = 64 q per block. All MFMA are 16x16x32 (verified cell).
// P goes C-layout -> LDS -> A-layout with explicit indices on both sides.
__global__ __launch_bounds__(256) void k_pass2(){
  __shared__ __align__(16) unsigned short Ks[64*64];     // [k][d]   swizzled
  __shared__ __align__(16) unsigned short Vs[64*64];     // [d][k]   swizzled
  __shared__ __align__(16) unsigned short Ps[4*16*64];   // per-wave [q][k] swizzled
  const int t = threadIdx.x, l = t & 63, wid = t >> 6;
  const int bh = blockIdx.y;
  const int b = bh >> 4, h = bh & 15;
  const int q0 = blockIdx.x * 64;
  const unsigned short* Qp = g_q16  + (size_t)bh * S_ * HD_;
  const unsigned short* Kp = g_k16  + (size_t)bh * S_ * HD_;
  const unsigned short* Vp = g_v16t + (size_t)bh * HD_ * S_;
  const int ql = l & 15;             // A/B-fragment row-or-col index
  const int kq = l >> 4;             // k-group 0..3
  const int qg = q0 + wid*16 + ql;   // this lane's global q row
  char* Pw = (char*)Ps + wid * 2048;

  bf16x8 qf[2];
  {
    const unsigned short* qr = Qp + (size_t)qg * HD_ + kq * 8;
    qf[0] = *(const bf16x8*)(qr);        // d in [0,32)
    qf[1] = *(const bf16x8*)(qr + 32);   // d in [32,64)
  }
  f32x4 co[4];
  #pragma unroll
  for (int nd = 0; nd < 4; ++nd)
    #pragma unroll
    for (int r = 0; r < 4; ++r) co[nd][r] = 0.f;

  const int srow = t >> 3, scb = (t & 7) * 16;
  float4 kreg[2], vreg[2];
  #pragma unroll
  for (int u = 0; u < 2; ++u){
    kreg[u] = *(const float4*)((const char*)(Kp + (size_t)(srow + u*32) * HD_) + scb);
    vreg[u] = *(const float4*)((const char*)(Vp + (size_t)(srow + u*32) * S_) + scb);
  }
  for (int kt = 0; kt < 32; ++kt){
    const int k0 = kt * 64;
    __syncthreads();
    #pragma unroll
    for (int u = 0; u < 2; ++u){
      const int row = srow + u*32;
      const int off = row*128 + (scb ^ ((row & 7) << 4));
      *(float4*)((char*)Ks + off) = kreg[u];
      *(float4*)((char*)Vs + off) = vreg[u];
    }
    __syncthreads();
    if (kt < 31){
      const int k1 = k0 + 64;
      #pragma unroll
      for (int u = 0; u < 2; ++u){
        kreg[u] = *(const float4*)((const char*)(Kp + (size_t)(k1 + srow + u*32) * HD_) + scb);
        vreg[u] = *(const float4*)((const char*)(Vp + (size_t)(srow + u*32) * S_ + k1) + scb);
      }
    }
    // ---- swapped QK^T: D[key16][q16] per kb; A = K rows, B = Q
    f32x4 cst[4];
    #pragma unroll
    for (int kb = 0; kb < 4; ++kb){
      #pragma unroll
      for (int r = 0; r < 4; ++r) cst[kb][r] = 0.f;
    }
    #pragma unroll
    for (int kb = 0; kb < 4; ++kb){
      #pragma unroll
      for (int s = 0; s < 2; ++s){
        const int row = kb*16 + ql;
        bf16x8 kf = *(const bf16x8*)((const char*)Ks + row*128 + ((s*64 + kq*16) ^ ((row & 7) << 4)));
        cst[kb] = MFMA16(kf, qf[s], cst[kb]);
      }
    }
    // ---- exp (+ zeroed diagonal => weight 1) -> bf16 pairs -> per-wave LDS
    #pragma unroll
    for (int kb = 0; kb < 4; ++kb){
      float e[4];
      #pragma unroll
      for (int r = 0; r < 4; ++r){
        const int key = k0 + kb*16 + kq*4 + r;   // C-layout: row=(lane>>4)*4+r
        const float ee = exp2f(cst[kb][r]);
        e[r] = (qg == key) ? 1.0f : ee;
      }
      uint2 w;
      w.x = pk2(e[0], e[1]);
      w.y = pk2(e[2], e[3]);
      *(uint2*)(Pw + ql*128 + ((kb*32 + kq*8) ^ ((ql & 7) << 4))) = w;
    }
    // ---- PV: D[q16][d16] ; A = P rows (from LDS), B = V' (k x d)
    #pragma unroll
    for (int sl = 0; sl < 2; ++sl){
      bf16x8 pf = *(const bf16x8*)(Pw + ql*128 + ((sl*64 + kq*16) ^ ((ql & 7) << 4)));
      #pragma unroll
      for (int nd = 0; nd < 4; ++nd){
        const int row = nd*16 + ql;   // d row in Vs
        bf16x8 vf = *(const bf16x8*)((const char*)Vs + row*128 + ((sl*64 + kq*16) ^ ((row & 7) << 4)));
        co[nd] = MFMA16(pf, vf, co[nd]);
      }
    }
  }
  // epilogue: C-layout col = ql = d-local, row = kq*4 + r = q-local
  #pragma unroll
  for (int nd = 0; nd < 4; ++nd){
    const int d = nd*16 + ql;
    #pragma unroll
    for (int r = 0; r < 4; ++r){
      const int q = q0 + wid*16 + kq*4 + r;
      g_x16[(size_t)(b*S_ + q) * D_ + h*HD_ + d] = f2b(co[nd][r]);
    }
  }
}

extern "C" void kernel_launch(void* const* d_in, const int* in_sizes, int n_in,
                              void* d_out, int out_size, void* d_ws, size_t ws_size,
                              hipStream_t stream) {
  const float* query = (const float*)d_in[0];
  const float* key   = (const float*)d_in[1];
  const float* value = (const float*)d_in[2];
  const int*   pos   = (const int*)  d_in[3];
  const float* Wk    = (const float*)d_in[4];
  const float* bk    = (const float*)d_in[5];
  const float* Wv    = (const float*)d_in[6];
  const float* bv    = (const float*)d_in[7];
  const float* Wo    = (const float*)d_in[8];
  const float* bo    = (const float*)d_in[9];
  float* out = (float*)d_out;

  unsigned short* pk16; hipGetSymbolAddress((void**)&pk16, HIP_SYMBOL(g_key16));
  unsigned short* pv16; hipGetSymbolAddress((void**)&pv16, HIP_SYMBOL(g_val16));
  unsigned short* pwk;  hipGetSymbolAddress((void**)&pwk,  HIP_SYMBOL(g_wk16));
  unsigned short* pwv;  hipGetSymbolAddress((void**)&pwv,  HIP_SYMBOL(g_wv16));
  unsigned short* pwo;  hipGetSymbolAddress((void**)&pwo,  HIP_SYMBOL(g_wo16));
  unsigned short* px16; hipGetSymbolAddress((void**)&px16, HIP_SYMBOL(g_x16));
  float* pkp; hipGetSymbolAddress((void**)&pkp, HIP_SYMBOL(g_kp));
  float* pvp; hipGetSymbolAddress((void**)&pvp, HIP_SYMBOL(g_vp));

  k_table<<<256, 256, 0, stream>>>(pos);

  k_cvt<<<2048, 256, 0, stream>>>(key,   pk16, (M_*D_)/8);
  k_cvt<<<2048, 256, 0, stream>>>(value, pv16, (M_*D_)/8);
  k_cvt<<<512,  256, 0, stream>>>(Wk, pwk, (D_*D_)/8);
  k_cvt<<<512,  256, 0, stream>>>(Wv, pwv, (D_*D_)/8);
  k_cvt<<<512,  256, 0, stream>>>(Wo, pwo, (D_*D_)/8);

  dim3 gG(D_/128, M_/128);     // (8, 32)
  k_gemm<<<gG, 256, 0, stream>>>(pk16, pwk, bk, pkp);   // key proj -> g_kp
  k_gemm<<<gG, 256, 0, stream>>>(pv16, pwv, bv, pvp);   // val proj -> g_vp

  k_rope16<0><<<8192, 256, 0, stream>>>(query);          // -> g_q16 (scaled)
  k_rope16<1><<<8192, 256, 0, stream>>>(nullptr);        // g_kp -> g_k16

  k_pass1<<<dim3(16, BH_), 256, 0, stream>>>();          // -> g_rz
  k_vfix <<<dim3(32, BH_), 256, 0, stream>>>();          // g_vp -> g_v16t
  k_pass2<<<dim3(32, BH_), 256, 0, stream>>>();          // -> g_x16

  k_gemm<<<gG, 256, 0, stream>>>(px16, pwo, bo, out);    // output proj
}

// Round 5
// 323.002 us; speedup vs baseline: 8.4570x; 1.2937x over previous
//
#include <hip/hip_runtime.h>
#include <hip/hip_bf16.h>
#include <math.h>

#define B_  2
#define S_  2048
#define D_  1024
#define H_  16
#define HD_ 64
#define M_  (B_*S_)      // 4096 (b,s) rows
#define BH_ (B_*H_)      // 32
#define QKSCALE 0.18033688011112042f   // 0.125 * log2(e), folded into Q

typedef __attribute__((ext_vector_type(8)))  short  bf16x8;
typedef __attribute__((ext_vector_type(4)))  float  f32x4;

#define MFMA16(a,b,c) __builtin_amdgcn_mfma_f32_16x16x32_bf16(a,b,c,0,0,0)

// ---- device scratch (~42 MB) ----
__device__ float          g_vp[(size_t)M_ * D_];     // roped V projection fp32
__device__ unsigned short g_q16[(size_t)M_ * D_];    // roped+scaled Q  [bh][s][64] (flat view)
__device__ unsigned short g_k16[(size_t)M_ * D_];    // roped K
__device__ unsigned short g_v16t[(size_t)M_ * D_];   // roped,*1/Z, V^T [bh][64 d][2048 s]
__device__ unsigned short g_x16[(size_t)M_ * D_];    // attn out, (b,s,D) layout
__device__ float          g_rz[BH_ * S_];            // 1/Z per (bh, key s)
__device__ float          g_tab[S_ * 64];            // cos/sin interleaved

static __device__ __forceinline__ unsigned short f2b(float x){
  union { float f; unsigned u; } v; v.f = x;
  unsigned r = v.u + 0x7FFFu + ((v.u >> 16) & 1u);   // RNE
  return (unsigned short)(r >> 16);
}
static __device__ __forceinline__ unsigned cvtpk(float lo, float hi){
  unsigned r;
  asm("v_cvt_pk_bf16_f32 %0, %1, %2" : "=v"(r) : "v"(lo), "v"(hi));
  return r;
}

// ------------------------------------------------ cos/sin table
__global__ void k_table(const int* __restrict__ pos){
  int i = blockIdx.x * 256 + threadIdx.x;
  if (i >= S_ * 32) return;
  int s = i >> 5, f = i & 31;
  float ang = (float)pos[s] * powf(10000.0f, -(float)f * (1.0f/32.0f));
  g_tab[2*i]   = cosf(ang);
  g_tab[2*i+1] = sinf(ang);
}

// ------------------------------------------------ Q: RoPE + scale -> bf16 (flat head view)
__global__ void k_ropeq(const float* __restrict__ in){
  const int i = blockIdx.x * 256 + threadIdx.x;   // pair index
  const int grp = i >> 5, d = i & 31;
  const int s = grp & (S_ - 1);                   // s' in (B,H,S,hd) view
  const size_t base = (size_t)grp * 64;
  const float x1 = in[base + d];
  const float x2 = in[base + d + 32];
  const float c  = g_tab[(s*32 + d)*2];
  const float sn = g_tab[(s*32 + d)*2 + 1];
  g_q16[base + d]      = f2b((x1*c - x2*sn) * QKSCALE);
  g_q16[base + d + 32] = f2b((x2*c + x1*sn) * QKSCALE);
}

// ------------------------------------------------ fused K/V projection GEMM (fp32 in, cvt-on-stage)
// z=0: C = rope(key @ Wk^T + bk) -> g_k16 (bf16)
// z=1: C = rope(value @ Wv^T + bv) -> g_vp (fp32)
// RoPE position: projection elem (s, dd) sits at head-view s' = (s&127)*16 + (dd>>6)
__global__ __launch_bounds__(256) void k_proj(const float* __restrict__ key,
                                              const float* __restrict__ value,
                                              const float* __restrict__ Wk,
                                              const float* __restrict__ bk,
                                              const float* __restrict__ Wv,
                                              const float* __restrict__ bv){
  __shared__ __align__(16) unsigned short As[128*64];
  __shared__ __align__(16) unsigned short Bs[128*64];
  const int z = blockIdx.z;
  const float* A    = z ? value : key;
  const float* W    = z ? Wv : Wk;
  const float* bias = z ? bv : bk;
  const int t = threadIdx.x, l = t & 63, wid = t >> 6;
  const int wm = wid >> 1, wn = wid & 1;
  const int rowB = blockIdx.y * 128, colB = blockIdx.x * 128;
  f32x4 acc[4][4];
  #pragma unroll
  for (int i = 0; i < 4; ++i)
    #pragma unroll
    for (int j = 0; j < 4; ++j)
      #pragma unroll
      for (int r = 0; r < 4; ++r) acc[i][j][r] = 0.f;

  const int srow = t >> 3, se = (t & 7) * 8;   // element offset within 64
  float4 a0[4], a1[4], b0[4], b1[4];
#define GLD(K0) \
  for (int u = 0; u < 4; ++u){ \
    const int row = srow + u*32; \
    const float* ap = A + (size_t)(rowB+row)*D_ + (K0) + se; \
    const float* wp = W + (size_t)(colB+row)*D_ + (K0) + se; \
    a0[u] = *(const float4*)ap; a1[u] = *(const float4*)(ap+4); \
    b0[u] = *(const float4*)wp; b1[u] = *(const float4*)(wp+4); \
  }
  GLD(0);
  for (int k0 = 0; k0 < D_; k0 += 64){
    __syncthreads();
    #pragma unroll
    for (int u = 0; u < 4; ++u){
      const int row = srow + u*32;
      const int off = row*128 + ((se*2) ^ ((row & 7) << 4));
      uint4 pa, pb;
      pa.x = cvtpk(a0[u].x, a0[u].y); pa.y = cvtpk(a0[u].z, a0[u].w);
      pa.z = cvtpk(a1[u].x, a1[u].y); pa.w = cvtpk(a1[u].z, a1[u].w);
      pb.x = cvtpk(b0[u].x, b0[u].y); pb.y = cvtpk(b0[u].z, b0[u].w);
      pb.z = cvtpk(b1[u].x, b1[u].y); pb.w = cvtpk(b1[u].z, b1[u].w);
      *(uint4*)((char*)As + off) = pa;
      *(uint4*)((char*)Bs + off) = pb;
    }
    __syncthreads();
    if (k0 + 64 < D_){ GLD(k0 + 64); }
    #pragma unroll
    for (int kk = 0; kk < 2; ++kk){
      const int cb = kk*64 + (l >> 4) * 16;
      bf16x8 af[4], bfr[4];
      #pragma unroll
      for (int mi = 0; mi < 4; ++mi){
        const int row = wm*64 + mi*16 + (l & 15);
        af[mi] = *(const bf16x8*)((const char*)As + row*128 + (cb ^ ((row & 7) << 4)));
      }
      #pragma unroll
      for (int ni = 0; ni < 4; ++ni){
        const int row = wn*64 + ni*16 + (l & 15);
        bfr[ni] = *(const bf16x8*)((const char*)Bs + row*128 + (cb ^ ((row & 7) << 4)));
      }
      #pragma unroll
      for (int mi = 0; mi < 4; ++mi)
        #pragma unroll
        for (int ni = 0; ni < 4; ++ni)
          acc[mi][ni] = MFMA16(af[mi], bfr[ni], acc[mi][ni]);
    }
  }
#undef GLD
  // epilogue: bias + RoPE (pairs are ni and ni+2: cols 32 apart within a head)
  const int ql15 = l & 15, r4 = (l >> 4) * 4;
  const int hcol = (colB >> 6) + wn;              // dd>>6, wave-uniform
  #pragma unroll
  for (int mi = 0; mi < 4; ++mi){
    #pragma unroll
    for (int r = 0; r < 4; ++r){
      const int row = rowB + wm*64 + mi*16 + r4 + r;
      const int pos = ((row & 127) << 4) + hcol;  // head-view position s'
      #pragma unroll
      for (int ni = 0; ni < 2; ++ni){
        const int col = colB + wn*64 + ni*16 + ql15;   // (col & 63) < 32
        const int f = ni*16 + ql15;
        const float c  = g_tab[(pos*32 + f)*2];
        const float sn = g_tab[(pos*32 + f)*2 + 1];
        const float x1 = acc[mi][ni][r]   + bias[col];
        const float x2 = acc[mi][ni+2][r] + bias[col+32];
        const float o1 = x1*c - x2*sn;
        const float o2 = x2*c + x1*sn;
        if (z){
          g_vp[(size_t)row*D_ + col]      = o1;
          g_vp[(size_t)row*D_ + col + 32] = o2;
        } else {
          g_k16[(size_t)row*D_ + col]      = f2b(o1);
          g_k16[(size_t)row*D_ + col + 32] = f2b(o2);
        }
      }
    }
  }
}

// ------------------------------------------------ output GEMM: out = x16 @ Wo^T + bo (Wo fp32, cvt-on-stage)
__global__ __launch_bounds__(256) void k_gemm_out(const unsigned short* __restrict__ A,
                                                  const float* __restrict__ W,
                                                  const float* __restrict__ bias,
                                                  float* __restrict__ C){
  __shared__ __align__(16) unsigned short As[128*64];
  __shared__ __align__(16) unsigned short Bs[128*64];
  const int t = threadIdx.x, l = t & 63, wid = t >> 6;
  const int wm = wid >> 1, wn = wid & 1;
  const int rowB = blockIdx.y * 128, colB = blockIdx.x * 128;
  f32x4 acc[4][4];
  #pragma unroll
  for (int i = 0; i < 4; ++i)
    #pragma unroll
    for (int j = 0; j < 4; ++j)
      #pragma unroll
      for (int r = 0; r < 4; ++r) acc[i][j][r] = 0.f;

  const int srow = t >> 3, se = (t & 7) * 8, scb = (t & 7) * 16;
  float4 ar[4], b0[4], b1[4];
#define GLD(K0) \
  for (int u = 0; u < 4; ++u){ \
    const int row = srow + u*32; \
    ar[u] = *(const float4*)((const char*)(A + (size_t)(rowB+row)*D_ + (K0)) + scb); \
    const float* wp = W + (size_t)(colB+row)*D_ + (K0) + se; \
    b0[u] = *(const float4*)wp; b1[u] = *(const float4*)(wp+4); \
  }
  GLD(0);
  for (int k0 = 0; k0 < D_; k0 += 64){
    __syncthreads();
    #pragma unroll
    for (int u = 0; u < 4; ++u){
      const int row = srow + u*32;
      const int off = row*128 + (scb ^ ((row & 7) << 4));
      uint4 pb;
      pb.x = cvtpk(b0[u].x, b0[u].y); pb.y = cvtpk(b0[u].z, b0[u].w);
      pb.z = cvtpk(b1[u].x, b1[u].y); pb.w = cvtpk(b1[u].z, b1[u].w);
      *(float4*)((char*)As + off) = ar[u];
      *(uint4*)((char*)Bs + off) = pb;
    }
    __syncthreads();
    if (k0 + 64 < D_){ GLD(k0 + 64); }
    #pragma unroll
    for (int kk = 0; kk < 2; ++kk){
      const int cb = kk*64 + (l >> 4) * 16;
      bf16x8 af[4], bfr[4];
      #pragma unroll
      for (int mi = 0; mi < 4; ++mi){
        const int row = wm*64 + mi*16 + (l & 15);
        af[mi] = *(const bf16x8*)((const char*)As + row*128 + (cb ^ ((row & 7) << 4)));
      }
      #pragma unroll
      for (int ni = 0; ni < 4; ++ni){
        const int row = wn*64 + ni*16 + (l & 15);
        bfr[ni] = *(const bf16x8*)((const char*)Bs + row*128 + (cb ^ ((row & 7) << 4)));
      }
      #pragma unroll
      for (int mi = 0; mi < 4; ++mi)
        #pragma unroll
        for (int ni = 0; ni < 4; ++ni)
          acc[mi][ni] = MFMA16(af[mi], bfr[ni], acc[mi][ni]);
    }
  }
#undef GLD
  #pragma unroll
  for (int mi = 0; mi < 4; ++mi){
    #pragma unroll
    for (int ni = 0; ni < 4; ++ni){
      const int col = colB + wn*64 + ni*16 + (l & 15);
      const float bb = bias[col];
      #pragma unroll
      for (int r = 0; r < 4; ++r){
        const int row = rowB + wm*64 + mi*16 + (l >> 4)*4 + r;
        C[(size_t)row * D_ + col] = acc[mi][ni][r] + bb;
      }
    }
  }
}

// ------------------------------------------------ pass 1: Z_k = sum_q exp(s_qk), diag s=0
// wave owns 64 key-columns in regs, streams all q from global.
__global__ __launch_bounds__(256) void k_pass1(){
  const int t = threadIdx.x, l = t & 63, wid = t >> 6;
  const int bh = blockIdx.y;
  const int kwb = blockIdx.x * 256 + wid * 64;
  const unsigned short* Qp = g_q16 + (size_t)bh * S_ * HD_;
  const unsigned short* Kp = g_k16 + (size_t)bh * S_ * HD_;
  bf16x8 bk_[4][2];
  #pragma unroll
  for (int kb = 0; kb < 4; ++kb){
    const unsigned short* kr = Kp + (size_t)(kwb + kb*16 + (l & 15)) * HD_ + (l >> 4) * 8;
    bk_[kb][0] = *(const bf16x8*)(kr);
    bk_[kb][1] = *(const bf16x8*)(kr + 32);
  }
  float zz[4] = {0.f, 0.f, 0.f, 0.f};
  for (int q0 = 0; q0 < S_; q0 += 16){
    const unsigned short* qr = Qp + (size_t)(q0 + (l & 15)) * HD_ + (l >> 4) * 8;
    bf16x8 a0 = *(const bf16x8*)(qr);
    bf16x8 a1 = *(const bf16x8*)(qr + 32);
    #pragma unroll
    for (int kb = 0; kb < 4; ++kb){
      f32x4 c = {0.f, 0.f, 0.f, 0.f};
      c = MFMA16(a0, bk_[kb][0], c);
      c = MFMA16(a1, bk_[kb][1], c);
      if (q0 == kwb + kb*16){          // wave-uniform: diagonal tile
        const int kg = kwb + kb*16 + (l & 15);
        #pragma unroll
        for (int r = 0; r < 4; ++r)
          zz[kb] += (q0 + (l >> 4)*4 + r == kg) ? 1.0f : exp2f(c[r]);
      } else {
        zz[kb] += exp2f(c[0]) + exp2f(c[1]) + exp2f(c[2]) + exp2f(c[3]);
      }
    }
  }
  #pragma unroll
  for (int kb = 0; kb < 4; ++kb){
    float z = zz[kb];
    z += __shfl_xor(z, 16); z += __shfl_xor(z, 32);
    if (l < 16) g_rz[bh*S_ + kwb + kb*16 + l] = 1.0f / z;
  }
}

// ------------------------------------------------ V fixup: *1/Z + transpose -> bf16 [bh][d][s] (already roped)
__global__ __launch_bounds__(256) void k_vfix(){
  __shared__ __align__(16) float tile[64][68];
  const int t = threadIdx.x;
  const int bh = blockIdx.y;
  const int s0 = blockIdx.x * 64;
  #pragma unroll
  for (int u = 0; u < 4; ++u){
    const int i = t + u*256;
    const int row = i >> 4, c4 = (i & 15) * 4;
    *(float4*)&tile[row][c4] = *(const float4*)(g_vp + (size_t)(bh*S_ + s0 + row) * HD_ + c4);
  }
  __syncthreads();
  const int d = t >> 2;
  const int sc = (t & 3) * 16;
  float rzv[16];
  #pragma unroll
  for (int u = 0; u < 4; ++u)
    *(float4*)&rzv[u*4] = *(const float4*)(g_rz + bh*S_ + s0 + sc + u*4);
  unsigned w[8];
  #pragma unroll
  for (int j2 = 0; j2 < 8; ++j2)
    w[j2] = cvtpk(tile[sc + 2*j2][d] * rzv[2*j2], tile[sc + 2*j2 + 1][d] * rzv[2*j2 + 1]);
  unsigned short* dst = g_v16t + (size_t)(bh*HD_ + d) * S_ + s0 + sc;
  *(uint4*)(dst)     = *(uint4*)&w[0];
  *(uint4*)(dst + 8) = *(uint4*)&w[4];
}

// ------------------------------------------------ pass 2: out[q,:] = sum_k exp(s_qk) * V'[k,:]
// 4 waves x 32 q-rows = 128 q per block. All MFMA 16x16x32.
__global__ __launch_bounds__(256) void k_pass2(){
  __shared__ __align__(16) unsigned short Ks[64*64];     // [k][d]   swizzled
  __shared__ __align__(16) unsigned short Vs[64*64];     // [d][k]   swizzled
  __shared__ __align__(16) unsigned short Ps[4*32*64];   // per-wave [q][k] swizzled
  const int t = threadIdx.x, l = t & 63, wid = t >> 6;
  const int bh = blockIdx.y;
  const int b = bh >> 4, hh = bh & 15;
  const int q0 = blockIdx.x * 128;
  const unsigned short* Qp = g_q16  + (size_t)bh * S_ * HD_;
  const unsigned short* Kp = g_k16  + (size_t)bh * S_ * HD_;
  const unsigned short* Vp = g_v16t + (size_t)bh * HD_ * S_;
  const int ql = l & 15, kq = l >> 4;
  const int qb = q0 + wid*32;
  char* Pw = (char*)Ps + wid * 4096;

  bf16x8 qf[2][2];
  #pragma unroll
  for (int h = 0; h < 2; ++h){
    const unsigned short* qr = Qp + (size_t)(qb + h*16 + ql) * HD_ + kq * 8;
    qf[h][0] = *(const bf16x8*)(qr);
    qf[h][1] = *(const bf16x8*)(qr + 32);
  }
  f32x4 co[4][2];
  #pragma unroll
  for (int nd = 0; nd < 4; ++nd)
    #pragma unroll
    for (int h = 0; h < 2; ++h)
      #pragma unroll
      for (int r = 0; r < 4; ++r) co[nd][h][r] = 0.f;

  const int srow = t >> 3, scb = (t & 7) * 16;
  float4 kreg[2], vreg[2];
  #pragma unroll
  for (int u = 0; u < 2; ++u){
    kreg[u] = *(const float4*)((const char*)(Kp + (size_t)(srow + u*32) * HD_) + scb);
    vreg[u] = *(const float4*)((const char*)(Vp + (size_t)(srow + u*32) * S_) + scb);
  }
  for (int kt = 0; kt < 32; ++kt){
    const int k0 = kt * 64;
    __syncthreads();
    #pragma unroll
    for (int u = 0; u < 2; ++u){
      const int row = srow + u*32;
      const int off = row*128 + (scb ^ ((row & 7) << 4));
      *(float4*)((char*)Ks + off) = kreg[u];
      *(float4*)((char*)Vs + off) = vreg[u];
    }
    __syncthreads();
    if (kt < 31){
      const int k1 = k0 + 64;
      #pragma unroll
      for (int u = 0; u < 2; ++u){
        kreg[u] = *(const float4*)((const char*)(Kp + (size_t)(k1 + srow + u*32) * HD_) + scb);
        vreg[u] = *(const float4*)((const char*)(Vp + (size_t)(srow + u*32) * S_ + k1) + scb);
      }
    }
    // ---- swapped QK^T: D[key16][q16]; A = K rows (shared across q-halves), B = Q
    f32x4 cst[4][2];
    #pragma unroll
    for (int kb = 0; kb < 4; ++kb)
      #pragma unroll
      for (int h = 0; h < 2; ++h)
        #pragma unroll
        for (int r = 0; r < 4; ++r) cst[kb][h][r] = 0.f;
    #pragma unroll
    for (int kb = 0; kb < 4; ++kb){
      const int row = kb*16 + ql;
      #pragma unroll
      for (int s = 0; s < 2; ++s){
        bf16x8 kf = *(const bf16x8*)((const char*)Ks + row*128 + ((s*64 + kq*16) ^ ((row & 7) << 4)));
        cst[kb][0] = MFMA16(kf, qf[0][s], cst[kb][0]);
        cst[kb][1] = MFMA16(kf, qf[1][s], cst[kb][1]);
      }
    }
    // ---- exp -> bf16 pairs -> per-wave LDS (diag handled on overlap tiles only; wave-uniform)
    const bool diag = (k0 < qb + 32) && (qb < k0 + 64);
    #pragma unroll
    for (int h = 0; h < 2; ++h){
      const int qg = qb + h*16 + ql;
      #pragma unroll
      for (int kb = 0; kb < 4; ++kb){
        float e[4];
        if (diag){
          #pragma unroll
          for (int r = 0; r < 4; ++r){
            const int key = k0 + kb*16 + kq*4 + r;
            e[r] = (qg == key) ? 1.0f : exp2f(cst[kb][h][r]);
          }
        } else {
          #pragma unroll
          for (int r = 0; r < 4; ++r) e[r] = exp2f(cst[kb][h][r]);
        }
        uint2 w;
        w.x = cvtpk(e[0], e[1]);
        w.y = cvtpk(e[2], e[3]);
        *(uint2*)(Pw + (h*16 + ql)*128 + ((kb*32 + kq*8) ^ ((ql & 7) << 4))) = w;
      }
    }
    // ---- PV: D[q16][d16]; A = P rows (LDS), B = V' (k x d), shared across q-halves
    #pragma unroll
    for (int sl = 0; sl < 2; ++sl){
      bf16x8 pf0 = *(const bf16x8*)(Pw + (0*16 + ql)*128 + ((sl*64 + kq*16) ^ ((ql & 7) << 4)));
      bf16x8 pf1 = *(const bf16x8*)(Pw + (1*16 + ql)*128 + ((sl*64 + kq*16) ^ ((ql & 7) << 4)));
      #pragma unroll
      for (int nd = 0; nd < 4; ++nd){
        const int row = nd*16 + ql;
        bf16x8 vf = *(const bf16x8*)((const char*)Vs + row*128 + ((sl*64 + kq*16) ^ ((row & 7) << 4)));
        co[nd][0] = MFMA16(pf0, vf, co[nd][0]);
        co[nd][1] = MFMA16(pf1, vf, co[nd][1]);
      }
    }
  }
  // epilogue
  #pragma unroll
  for (int h = 0; h < 2; ++h){
    #pragma unroll
    for (int nd = 0; nd < 4; ++nd){
      const int d = nd*16 + ql;
      #pragma unroll
      for (int r = 0; r < 4; ++r){
        const int q = qb + h*16 + kq*4 + r;
        g_x16[(size_t)(b*S_ + q) * D_ + hh*HD_ + d] = f2b(co[nd][h][r]);
      }
    }
  }
}

extern "C" void kernel_launch(void* const* d_in, const int* in_sizes, int n_in,
                              void* d_out, int out_size, void* d_ws, size_t ws_size,
                              hipStream_t stream) {
  const float* query = (const float*)d_in[0];
  const float* key   = (const float*)d_in[1];
  const float* value = (const float*)d_in[2];
  const int*   pos   = (const int*)  d_in[3];
  const float* Wk    = (const float*)d_in[4];
  const float* bk    = (const float*)d_in[5];
  const float* Wv    = (const float*)d_in[6];
  const float* bv    = (const float*)d_in[7];
  const float* Wo    = (const float*)d_in[8];
  const float* bo    = (const float*)d_in[9];
  float* out = (float*)d_out;

  unsigned short* px16; hipGetSymbolAddress((void**)&px16, HIP_SYMBOL(g_x16));

  k_table<<<256, 256, 0, stream>>>(pos);

  dim3 gP(D_/128, M_/128, 2);   // (8, 32, 2)
  k_proj<<<gP, 256, 0, stream>>>(key, value, Wk, bk, Wv, bv);  // -> g_k16 (roped bf16), g_vp (roped fp32)

  k_ropeq<<<8192, 256, 0, stream>>>(query);                    // -> g_q16 (roped, scaled)

  k_pass1<<<dim3(8, BH_), 256, 0, stream>>>();                 // -> g_rz
  k_vfix <<<dim3(32, BH_), 256, 0, stream>>>();                // g_vp -> g_v16t (*1/Z, transposed)
  k_pass2<<<dim3(16, BH_), 256, 0, stream>>>();                // -> g_x16

  dim3 gO(D_/128, M_/128);      // (8, 32)
  k_gemm_out<<<gO, 256, 0, stream>>>(px16, Wo, bo, out);       // output proj
}

// Round 6
// 246.520 us; speedup vs baseline: 11.0807x; 1.3102x over previous
//
#include <hip/hip_runtime.h>
#include <hip/hip_bf16.h>
#include <math.h>

#define B_  2
#define S_  2048
#define D_  1024
#define H_  16
#define HD_ 64
#define M_  (B_*S_)      // 4096 (b,s) rows
#define BH_ (B_*H_)      // 32
#define QKSCALE 0.18033688011112042f   // 0.125 * log2(e), folded into Q

typedef __attribute__((ext_vector_type(8)))  short  bf16x8;
typedef __attribute__((ext_vector_type(4)))  float  f32x4;

#define MFMA16(a,b,c) __builtin_amdgcn_mfma_f32_16x16x32_bf16(a,b,c,0,0,0)

// ---- device scratch (~64 MB) ----
__device__ float          g_vp[(size_t)M_ * D_];     // roped V projection fp32; later PV partial z=0
__device__ float          g_p1[(size_t)M_ * D_];     // PV partial z=1
__device__ unsigned short g_q16[(size_t)M_ * D_];    // roped+scaled Q  [bh][s][64] (flat view)
__device__ unsigned short g_k16[(size_t)M_ * D_];    // roped K
__device__ unsigned short g_v16t[(size_t)M_ * D_];   // roped,*1/Z, V^T [bh][64 d][2048 s]
__device__ unsigned short g_x16[(size_t)M_ * D_];    // attn out, (b,s,D) layout
__device__ float          g_rz[BH_ * S_];            // 1/Z per (bh, key s)
__device__ float          g_tab[S_ * 64];            // cos/sin interleaved

static __device__ __forceinline__ unsigned short f2b(float x){
  union { float f; unsigned u; } v; v.f = x;
  unsigned r = v.u + 0x7FFFu + ((v.u >> 16) & 1u);   // RNE
  return (unsigned short)(r >> 16);
}
static __device__ __forceinline__ unsigned cvtpk(float lo, float hi){
  unsigned r;
  asm("v_cvt_pk_bf16_f32 %0, %1, %2" : "=v"(r) : "v"(lo), "v"(hi));
  return r;
}

// ------------------------------------------------ cos/sin table
__global__ void k_table(const int* __restrict__ pos){
  int i = blockIdx.x * 256 + threadIdx.x;
  if (i >= S_ * 32) return;
  int s = i >> 5, f = i & 31;
  float ang = (float)pos[s] * powf(10000.0f, -(float)f * (1.0f/32.0f));
  g_tab[2*i]   = cosf(ang);
  g_tab[2*i+1] = sinf(ang);
}

// ------------------------------------------------ Q: RoPE + scale -> bf16 (flat head view)
__global__ void k_ropeq(const float* __restrict__ in){
  const int i = blockIdx.x * 256 + threadIdx.x;   // pair index
  const int grp = i >> 5, d = i & 31;
  const int s = grp & (S_ - 1);                   // s' in (B,H,S,hd) view
  const size_t base = (size_t)grp * 64;
  const float x1 = in[base + d];
  const float x2 = in[base + d + 32];
  const float c  = g_tab[(s*32 + d)*2];
  const float sn = g_tab[(s*32 + d)*2 + 1];
  g_q16[base + d]      = f2b((x1*c - x2*sn) * QKSCALE);
  g_q16[base + d + 32] = f2b((x2*c + x1*sn) * QKSCALE);
}

// ------------------------------------------------ fused K/V projection GEMM (fp32 in, cvt-on-stage)
// z=0: C = rope(key @ Wk^T + bk) -> g_k16 (bf16)
// z=1: C = rope(value @ Wv^T + bv) -> g_vp (fp32)
// RoPE position: projection elem (s, dd) sits at head-view s' = (s&127)*16 + (dd>>6)
__global__ __launch_bounds__(256) void k_proj(const float* __restrict__ key,
                                              const float* __restrict__ value,
                                              const float* __restrict__ Wk,
                                              const float* __restrict__ bk,
                                              const float* __restrict__ Wv,
                                              const float* __restrict__ bv){
  __shared__ __align__(16) unsigned short As[128*64];
  __shared__ __align__(16) unsigned short Bs[128*64];
  const int z = blockIdx.z;
  const float* A    = z ? value : key;
  const float* W    = z ? Wv : Wk;
  const float* bias = z ? bv : bk;
  const int t = threadIdx.x, l = t & 63, wid = t >> 6;
  const int wm = wid >> 1, wn = wid & 1;
  const int rowB = blockIdx.y * 128, colB = blockIdx.x * 128;
  f32x4 acc[4][4];
  #pragma unroll
  for (int i = 0; i < 4; ++i)
    #pragma unroll
    for (int j = 0; j < 4; ++j)
      #pragma unroll
      for (int r = 0; r < 4; ++r) acc[i][j][r] = 0.f;

  const int srow = t >> 3, se = (t & 7) * 8;   // element offset within 64
  float4 a0[4], a1[4], b0[4], b1[4];
#define GLD(K0) \
  for (int u = 0; u < 4; ++u){ \
    const int row = srow + u*32; \
    const float* ap = A + (size_t)(rowB+row)*D_ + (K0) + se; \
    const float* wp = W + (size_t)(colB+row)*D_ + (K0) + se; \
    a0[u] = *(const float4*)ap; a1[u] = *(const float4*)(ap+4); \
    b0[u] = *(const float4*)wp; b1[u] = *(const float4*)(wp+4); \
  }
  GLD(0);
  for (int k0 = 0; k0 < D_; k0 += 64){
    __syncthreads();
    #pragma unroll
    for (int u = 0; u < 4; ++u){
      const int row = srow + u*32;
      const int off = row*128 + ((se*2) ^ ((row & 7) << 4));
      uint4 pa, pb;
      pa.x = cvtpk(a0[u].x, a0[u].y); pa.y = cvtpk(a0[u].z, a0[u].w);
      pa.z = cvtpk(a1[u].x, a1[u].y); pa.w = cvtpk(a1[u].z, a1[u].w);
      pb.x = cvtpk(b0[u].x, b0[u].y); pb.y = cvtpk(b0[u].z, b0[u].w);
      pb.z = cvtpk(b1[u].x, b1[u].y); pb.w = cvtpk(b1[u].z, b1[u].w);
      *(uint4*)((char*)As + off) = pa;
      *(uint4*)((char*)Bs + off) = pb;
    }
    __syncthreads();
    if (k0 + 64 < D_){ GLD(k0 + 64); }
    #pragma unroll
    for (int kk = 0; kk < 2; ++kk){
      const int cb = kk*64 + (l >> 4) * 16;
      bf16x8 af[4], bfr[4];
      #pragma unroll
      for (int mi = 0; mi < 4; ++mi){
        const int row = wm*64 + mi*16 + (l & 15);
        af[mi] = *(const bf16x8*)((const char*)As + row*128 + (cb ^ ((row & 7) << 4)));
      }
      #pragma unroll
      for (int ni = 0; ni < 4; ++ni){
        const int row = wn*64 + ni*16 + (l & 15);
        bfr[ni] = *(const bf16x8*)((const char*)Bs + row*128 + (cb ^ ((row & 7) << 4)));
      }
      #pragma unroll
      for (int mi = 0; mi < 4; ++mi)
        #pragma unroll
        for (int ni = 0; ni < 4; ++ni)
          acc[mi][ni] = MFMA16(af[mi], bfr[ni], acc[mi][ni]);
    }
  }
#undef GLD
  // epilogue: bias + RoPE (pairs are ni and ni+2: cols 32 apart within a head)
  const int ql15 = l & 15, r4 = (l >> 4) * 4;
  const int hcol = (colB >> 6) + wn;              // dd>>6, wave-uniform
  #pragma unroll
  for (int mi = 0; mi < 4; ++mi){
    #pragma unroll
    for (int r = 0; r < 4; ++r){
      const int row = rowB + wm*64 + mi*16 + r4 + r;
      const int pos = ((row & 127) << 4) + hcol;  // head-view position s'
      #pragma unroll
      for (int ni = 0; ni < 2; ++ni){
        const int col = colB + wn*64 + ni*16 + ql15;   // (col & 63) < 32
        const int f = ni*16 + ql15;
        const float c  = g_tab[(pos*32 + f)*2];
        const float sn = g_tab[(pos*32 + f)*2 + 1];
        const float x1 = acc[mi][ni][r]   + bias[col];
        const float x2 = acc[mi][ni+2][r] + bias[col+32];
        const float o1 = x1*c - x2*sn;
        const float o2 = x2*c + x1*sn;
        if (z){
          g_vp[(size_t)row*D_ + col]      = o1;
          g_vp[(size_t)row*D_ + col + 32] = o2;
        } else {
          g_k16[(size_t)row*D_ + col]      = f2b(o1);
          g_k16[(size_t)row*D_ + col + 32] = f2b(o2);
        }
      }
    }
  }
}

// ------------------------------------------------ output GEMM: out = x16 @ Wo^T + bo (Wo fp32, cvt-on-stage)
__global__ __launch_bounds__(256) void k_gemm_out(const unsigned short* __restrict__ A,
                                                  const float* __restrict__ W,
                                                  const float* __restrict__ bias,
                                                  float* __restrict__ C){
  __shared__ __align__(16) unsigned short As[128*64];
  __shared__ __align__(16) unsigned short Bs[128*64];
  const int t = threadIdx.x, l = t & 63, wid = t >> 6;
  const int wm = wid >> 1, wn = wid & 1;
  const int rowB = blockIdx.y * 128, colB = blockIdx.x * 128;
  f32x4 acc[4][4];
  #pragma unroll
  for (int i = 0; i < 4; ++i)
    #pragma unroll
    for (int j = 0; j < 4; ++j)
      #pragma unroll
      for (int r = 0; r < 4; ++r) acc[i][j][r] = 0.f;

  const int srow = t >> 3, se = (t & 7) * 8, scb = (t & 7) * 16;
  float4 ar[4], b0[4], b1[4];
#define GLD(K0) \
  for (int u = 0; u < 4; ++u){ \
    const int row = srow + u*32; \
    ar[u] = *(const float4*)((const char*)(A + (size_t)(rowB+row)*D_ + (K0)) + scb); \
    const float* wp = W + (size_t)(colB+row)*D_ + (K0) + se; \
    b0[u] = *(const float4*)wp; b1[u] = *(const float4*)(wp+4); \
  }
  GLD(0);
  for (int k0 = 0; k0 < D_; k0 += 64){
    __syncthreads();
    #pragma unroll
    for (int u = 0; u < 4; ++u){
      const int row = srow + u*32;
      const int off = row*128 + (scb ^ ((row & 7) << 4));
      uint4 pb;
      pb.x = cvtpk(b0[u].x, b0[u].y); pb.y = cvtpk(b0[u].z, b0[u].w);
      pb.z = cvtpk(b1[u].x, b1[u].y); pb.w = cvtpk(b1[u].z, b1[u].w);
      *(float4*)((char*)As + off) = ar[u];
      *(uint4*)((char*)Bs + off) = pb;
    }
    __syncthreads();
    if (k0 + 64 < D_){ GLD(k0 + 64); }
    #pragma unroll
    for (int kk = 0; kk < 2; ++kk){
      const int cb = kk*64 + (l >> 4) * 16;
      bf16x8 af[4], bfr[4];
      #pragma unroll
      for (int mi = 0; mi < 4; ++mi){
        const int row = wm*64 + mi*16 + (l & 15);
        af[mi] = *(const bf16x8*)((const char*)As + row*128 + (cb ^ ((row & 7) << 4)));
      }
      #pragma unroll
      for (int ni = 0; ni < 4; ++ni){
        const int row = wn*64 + ni*16 + (l & 15);
        bfr[ni] = *(const bf16x8*)((const char*)Bs + row*128 + (cb ^ ((row & 7) << 4)));
      }
      #pragma unroll
      for (int mi = 0; mi < 4; ++mi)
        #pragma unroll
        for (int ni = 0; ni < 4; ++ni)
          acc[mi][ni] = MFMA16(af[mi], bfr[ni], acc[mi][ni]);
    }
  }
#undef GLD
  #pragma unroll
  for (int mi = 0; mi < 4; ++mi){
    #pragma unroll
    for (int ni = 0; ni < 4; ++ni){
      const int col = colB + wn*64 + ni*16 + (l & 15);
      const float bb = bias[col];
      #pragma unroll
      for (int r = 0; r < 4; ++r){
        const int row = rowB + wm*64 + mi*16 + (l >> 4)*4 + r;
        C[(size_t)row * D_ + col] = acc[mi][ni][r] + bb;
      }
    }
  }
}

// ------------------------------------------------ pass 1: Z_k = sum_q exp(s_qk), diag s=0
// block = 4 waves on the SAME 64 keys; each wave sums a 512-q quarter; LDS combine.
__global__ __launch_bounds__(256) void k_pass1(){
  __shared__ float zs[4][4][16];
  const int t = threadIdx.x, l = t & 63, wid = t >> 6;
  const int bh = blockIdx.y;
  const int kwb = blockIdx.x * 64;
  const unsigned short* Qp = g_q16 + (size_t)bh * S_ * HD_;
  const unsigned short* Kp = g_k16 + (size_t)bh * S_ * HD_;
  bf16x8 bk_[4][2];
  #pragma unroll
  for (int kb = 0; kb < 4; ++kb){
    const unsigned short* kr = Kp + (size_t)(kwb + kb*16 + (l & 15)) * HD_ + (l >> 4) * 8;
    bk_[kb][0] = *(const bf16x8*)(kr);
    bk_[kb][1] = *(const bf16x8*)(kr + 32);
  }
  float zz[4] = {0.f, 0.f, 0.f, 0.f};
  const int qBeg = wid * (S_/4);
  for (int qi = 0; qi < S_/4; qi += 16){
    const int q0 = qBeg + qi;
    const unsigned short* qr = Qp + (size_t)(q0 + (l & 15)) * HD_ + (l >> 4) * 8;
    bf16x8 a0 = *(const bf16x8*)(qr);
    bf16x8 a1 = *(const bf16x8*)(qr + 32);
    #pragma unroll
    for (int kb = 0; kb < 4; ++kb){
      f32x4 c = {0.f, 0.f, 0.f, 0.f};
      c = MFMA16(a0, bk_[kb][0], c);
      c = MFMA16(a1, bk_[kb][1], c);
      if (q0 == kwb + kb*16){          // wave-uniform: diagonal tile
        const int kg = kwb + kb*16 + (l & 15);
        #pragma unroll
        for (int r = 0; r < 4; ++r)
          zz[kb] += (q0 + (l >> 4)*4 + r == kg) ? 1.0f : exp2f(c[r]);
      } else {
        zz[kb] += exp2f(c[0]) + exp2f(c[1]) + exp2f(c[2]) + exp2f(c[3]);
      }
    }
  }
  #pragma unroll
  for (int kb = 0; kb < 4; ++kb){
    float z = zz[kb];
    z += __shfl_xor(z, 16); z += __shfl_xor(z, 32);
    if (l < 16) zs[wid][kb][l] = z;
  }
  __syncthreads();
  if (t < 64){
    const int kb = t >> 4, ki = t & 15;
    const float Z = zs[0][kb][ki] + zs[1][kb][ki] + zs[2][kb][ki] + zs[3][kb][ki];
    g_rz[bh*S_ + kwb + kb*16 + ki] = 1.0f / Z;
  }
}

// ------------------------------------------------ V fixup: *1/Z + transpose -> bf16 [bh][d][s] (already roped)
__global__ __launch_bounds__(256) void k_vfix(){
  __shared__ __align__(16) float tile[64][68];
  const int t = threadIdx.x;
  const int bh = blockIdx.y;
  const int s0 = blockIdx.x * 64;
  #pragma unroll
  for (int u = 0; u < 4; ++u){
    const int i = t + u*256;
    const int row = i >> 4, c4 = (i & 15) * 4;
    *(float4*)&tile[row][c4] = *(const float4*)(g_vp + (size_t)(bh*S_ + s0 + row) * HD_ + c4);
  }
  __syncthreads();
  const int d = t >> 2;
  const int sc = (t & 3) * 16;
  float rzv[16];
  #pragma unroll
  for (int u = 0; u < 4; ++u)
    *(float4*)&rzv[u*4] = *(const float4*)(g_rz + bh*S_ + s0 + sc + u*4);
  unsigned w[8];
  #pragma unroll
  for (int j2 = 0; j2 < 8; ++j2)
    w[j2] = cvtpk(tile[sc + 2*j2][d] * rzv[2*j2], tile[sc + 2*j2 + 1][d] * rzv[2*j2 + 1]);
  unsigned short* dst = g_v16t + (size_t)(bh*HD_ + d) * S_ + s0 + sc;
  *(uint4*)(dst)     = *(uint4*)&w[0];
  *(uint4*)(dst + 8) = *(uint4*)&w[4];
}

// ------------------------------------------------ pass 2: out[q,:] = sum_k exp(s_qk) * V'[k,:]
// 4 waves x 32 q; blockIdx.z splits the key range in halves (fp32 partial outputs).
__global__ __launch_bounds__(256, 4) void k_pass2(){
  __shared__ __align__(16) unsigned short Ks[64*64];     // [k][d]   swizzled
  __shared__ __align__(16) unsigned short Vs[64*64];     // [d][k]   swizzled
  __shared__ __align__(16) unsigned short Ps[4*32*64];   // per-wave [q][k] swizzled
  const int t = threadIdx.x, l = t & 63, wid = t >> 6;
  const int bh = blockIdx.y;
  const int z = blockIdx.z;
  const int b = bh >> 4, hh = bh & 15;
  const int q0 = blockIdx.x * 128;
  const unsigned short* Qp = g_q16  + (size_t)bh * S_ * HD_;
  const unsigned short* Kp = g_k16  + (size_t)bh * S_ * HD_;
  const unsigned short* Vp = g_v16t + (size_t)bh * HD_ * S_;
  float* Op = z ? g_p1 : g_vp;
  const int ql = l & 15, kq = l >> 4;
  const int qb = q0 + wid*32;
  char* Pw = (char*)Ps + wid * 4096;

  bf16x8 qf[2][2];
  #pragma unroll
  for (int h = 0; h < 2; ++h){
    const unsigned short* qr = Qp + (size_t)(qb + h*16 + ql) * HD_ + kq * 8;
    qf[h][0] = *(const bf16x8*)(qr);
    qf[h][1] = *(const bf16x8*)(qr + 32);
  }
  f32x4 co[4][2];
  #pragma unroll
  for (int nd = 0; nd < 4; ++nd)
    #pragma unroll
    for (int h = 0; h < 2; ++h)
      #pragma unroll
      for (int r = 0; r < 4; ++r) co[nd][h][r] = 0.f;

  const int srow = t >> 3, scb = (t & 7) * 16;
  const int kg0 = z * (S_/2);
  float4 kreg[2], vreg[2];
  #pragma unroll
  for (int u = 0; u < 2; ++u){
    kreg[u] = *(const float4*)((const char*)(Kp + (size_t)(kg0 + srow + u*32) * HD_) + scb);
    vreg[u] = *(const float4*)((const char*)(Vp + (size_t)(srow + u*32) * S_ + kg0) + scb);
  }
  for (int kt = 0; kt < 16; ++kt){
    const int k0 = kg0 + kt * 64;
    __syncthreads();
    #pragma unroll
    for (int u = 0; u < 2; ++u){
      const int row = srow + u*32;
      const int off = row*128 + (scb ^ ((row & 7) << 4));
      *(float4*)((char*)Ks + off) = kreg[u];
      *(float4*)((char*)Vs + off) = vreg[u];
    }
    __syncthreads();
    if (kt < 15){
      const int k1 = k0 + 64;
      #pragma unroll
      for (int u = 0; u < 2; ++u){
        kreg[u] = *(const float4*)((const char*)(Kp + (size_t)(k1 + srow + u*32) * HD_) + scb);
        vreg[u] = *(const float4*)((const char*)(Vp + (size_t)(srow + u*32) * S_ + k1) + scb);
      }
    }
    // ---- swapped QK^T: D[key16][q16]; A = K rows (shared across q-halves), B = Q
    f32x4 cst[4][2];
    #pragma unroll
    for (int kb = 0; kb < 4; ++kb)
      #pragma unroll
      for (int h = 0; h < 2; ++h)
        #pragma unroll
        for (int r = 0; r < 4; ++r) cst[kb][h][r] = 0.f;
    #pragma unroll
    for (int kb = 0; kb < 4; ++kb){
      const int row = kb*16 + ql;
      #pragma unroll
      for (int s = 0; s < 2; ++s){
        bf16x8 kf = *(const bf16x8*)((const char*)Ks + row*128 + ((s*64 + kq*16) ^ ((row & 7) << 4)));
        cst[kb][0] = MFMA16(kf, qf[0][s], cst[kb][0]);
        cst[kb][1] = MFMA16(kf, qf[1][s], cst[kb][1]);
      }
    }
    // ---- exp -> bf16 pairs -> per-wave LDS (diag handled on overlap tiles only; wave-uniform)
    const bool diag = (k0 < qb + 32) && (qb < k0 + 64);
    #pragma unroll
    for (int h = 0; h < 2; ++h){
      const int qg = qb + h*16 + ql;
      #pragma unroll
      for (int kb = 0; kb < 4; ++kb){
        float e[4];
        if (diag){
          #pragma unroll
          for (int r = 0; r < 4; ++r){
            const int key = k0 + kb*16 + kq*4 + r;
            e[r] = (qg == key) ? 1.0f : exp2f(cst[kb][h][r]);
          }
        } else {
          #pragma unroll
          for (int r = 0; r < 4; ++r) e[r] = exp2f(cst[kb][h][r]);
        }
        uint2 w;
        w.x = cvtpk(e[0], e[1]);
        w.y = cvtpk(e[2], e[3]);
        *(uint2*)(Pw + (h*16 + ql)*128 + ((kb*32 + kq*8) ^ ((ql & 7) << 4))) = w;
      }
    }
    // ---- PV: D[q16][d16]; A = P rows (LDS), B = V' (k x d), shared across q-halves
    #pragma unroll
    for (int sl = 0; sl < 2; ++sl){
      bf16x8 pf0 = *(const bf16x8*)(Pw + (0*16 + ql)*128 + ((sl*64 + kq*16) ^ ((ql & 7) << 4)));
      bf16x8 pf1 = *(const bf16x8*)(Pw + (1*16 + ql)*128 + ((sl*64 + kq*16) ^ ((ql & 7) << 4)));
      #pragma unroll
      for (int nd = 0; nd < 4; ++nd){
        const int row = nd*16 + ql;
        bf16x8 vf = *(const bf16x8*)((const char*)Vs + row*128 + ((sl*64 + kq*16) ^ ((row & 7) << 4)));
        co[nd][0] = MFMA16(pf0, vf, co[nd][0]);
        co[nd][1] = MFMA16(pf1, vf, co[nd][1]);
      }
    }
  }
  // epilogue: fp32 partial, (b,s,D) layout
  #pragma unroll
  for (int h = 0; h < 2; ++h){
    #pragma unroll
    for (int nd = 0; nd < 4; ++nd){
      const int d = nd*16 + ql;
      #pragma unroll
      for (int r = 0; r < 4; ++r){
        const int q = qb + h*16 + kq*4 + r;
        Op[(size_t)(b*S_ + q) * D_ + hh*HD_ + d] = co[nd][h][r];
      }
    }
  }
}

// ------------------------------------------------ combine PV partials -> bf16
__global__ void k_reduce(){
  const int i = blockIdx.x * 256 + threadIdx.x;
  const size_t off = (size_t)i * 8;
  float4 a0 = *(const float4*)(g_vp + off), a1 = *(const float4*)(g_vp + off + 4);
  float4 b0 = *(const float4*)(g_p1 + off), b1 = *(const float4*)(g_p1 + off + 4);
  uint4 w;
  w.x = cvtpk(a0.x + b0.x, a0.y + b0.y);
  w.y = cvtpk(a0.z + b0.z, a0.w + b0.w);
  w.z = cvtpk(a1.x + b1.x, a1.y + b1.y);
  w.w = cvtpk(a1.z + b1.z, a1.w + b1.w);
  *(uint4*)(g_x16 + off) = w;
}

extern "C" void kernel_launch(void* const* d_in, const int* in_sizes, int n_in,
                              void* d_out, int out_size, void* d_ws, size_t ws_size,
                              hipStream_t stream) {
  const float* query = (const float*)d_in[0];
  const float* key   = (const float*)d_in[1];
  const float* value = (const float*)d_in[2];
  const int*   pos   = (const int*)  d_in[3];
  const float* Wk    = (const float*)d_in[4];
  const float* bk    = (const float*)d_in[5];
  const float* Wv    = (const float*)d_in[6];
  const float* bv    = (const float*)d_in[7];
  const float* Wo    = (const float*)d_in[8];
  const float* bo    = (const float*)d_in[9];
  float* out = (float*)d_out;

  unsigned short* px16; hipGetSymbolAddress((void**)&px16, HIP_SYMBOL(g_x16));

  k_table<<<256, 256, 0, stream>>>(pos);

  dim3 gP(D_/128, M_/128, 2);   // (8, 32, 2)
  k_proj<<<gP, 256, 0, stream>>>(key, value, Wk, bk, Wv, bv);  // -> g_k16 (roped bf16), g_vp (roped fp32)

  k_ropeq<<<8192, 256, 0, stream>>>(query);                    // -> g_q16 (roped, scaled)

  k_pass1<<<dim3(S_/64, BH_), 256, 0, stream>>>();             // -> g_rz   (1024 blocks)
  k_vfix <<<dim3(32, BH_), 256, 0, stream>>>();                // g_vp -> g_v16t (*1/Z, transposed)
  k_pass2<<<dim3(16, BH_, 2), 256, 0, stream>>>();             // -> g_vp/g_p1 fp32 partials (1024 blocks)
  k_reduce<<<(M_*D_/8)/256, 256, 0, stream>>>();               // -> g_x16

  dim3 gO(D_/128, M_/128);      // (8, 32)
  k_gemm_out<<<gO, 256, 0, stream>>>(px16, Wo, bo, out);       // output proj
}